// Round 11
// baseline (27.228 us; speedup 1.0000x reference)
//
#include <hip/hip_runtime.h>
#include <hip/hip_bf16.h>

#define TT 8192
#define DD 64
#define NTILE 64                        // 8192 / 128
#define NBLK (NTILE * (NTILE + 1) / 2)  // 2080 upper-tri 128x128 tiles
#define NQUAD (NBLK / 4)                // 520 blocks, 4 tiles each
#define NPREP 256                       // prep blocks (32 rows each)
#define L2E 1.4426950408889634f

typedef __attribute__((ext_vector_type(8))) short short8;
typedef __attribute__((ext_vector_type(4))) float f32x4;

static __device__ __forceinline__ float fast_exp2(float x) {
#if __has_builtin(__builtin_amdgcn_exp2f)
    return __builtin_amdgcn_exp2f(x);
#else
    float r; asm volatile("v_exp_f32 %0, %1" : "=v"(r) : "v"(x)); return r;
#endif
}

// Fragment-ready layout: for rowgroup rg = row/16, ks = k/32:
//   flat elem index = (rg*2 + ks)*512 + ((k%32)/8)*128 + (row%16)*8 + (k%8)
// A wave's MFMA fragment load for (rg, ks) is xf_base + lane*8 elems --
// one contiguous 1 KB burst per instruction.
//
// ws layout:
//   [0]        float sq2[8192]     (L2E * ||x_i||^2)
//   [+32KB]    short xf[8192*64]   (1 MB, fragment-tiled bf16)
//   [+32KB+1MB]float p1[520]; float p3[256]

__global__ __launch_bounds__(256) void prep_kernel(const float* __restrict__ x,
                                                   float* __restrict__ sq2,
                                                   short* __restrict__ xf,
                                                   float* __restrict__ p3) {
    const int tid = threadIdx.x;
    const int r   = tid >> 3;           // 0..31 row within block
    const int ch  = tid & 7;            // 0..7, 8-element k-chunk
    const int row = blockIdx.x * 32 + r;

    const float4 u = *(const float4*)(x + (size_t)row * DD + ch * 8);
    const float4 v = *(const float4*)(x + (size_t)row * DD + ch * 8 + 4);
    short8 s8;
    s8[0] = __builtin_bit_cast(short, __float2bfloat16(u.x));
    s8[1] = __builtin_bit_cast(short, __float2bfloat16(u.y));
    s8[2] = __builtin_bit_cast(short, __float2bfloat16(u.z));
    s8[3] = __builtin_bit_cast(short, __float2bfloat16(u.w));
    s8[4] = __builtin_bit_cast(short, __float2bfloat16(v.x));
    s8[5] = __builtin_bit_cast(short, __float2bfloat16(v.y));
    s8[6] = __builtin_bit_cast(short, __float2bfloat16(v.z));
    s8[7] = __builtin_bit_cast(short, __float2bfloat16(v.w));

    const size_t F = (size_t)(row >> 4) * 1024 + (size_t)(ch >> 2) * 512
                   + (size_t)(ch & 3) * 128 + (size_t)(row & 15) * 8;
    *(short8*)(xf + F) = s8;

    float s = u.x*u.x + u.y*u.y + u.z*u.z + u.w*u.w
            + v.x*v.x + v.y*v.y + v.z*v.z + v.w*v.w;
    s += __shfl_xor(s, 1, 64);
    s += __shfl_xor(s, 2, 64);
    s += __shfl_xor(s, 4, 64);

    __shared__ float e3[32];
    if (ch == 0) {
        sq2[row] = L2E * s;
        e3[r] = __expf(s);
    }
    __syncthreads();
    if (tid == 0) {
        float t = 0.f;
        #pragma unroll
        for (int i = 0; i < 32; i++) t += e3[i];
        p3[blockIdx.x] = t;
    }
}

// 1024 threads = 16 waves; wave wid owns tile 4*blockIdx + (wid>>2),
// quadrant wid&3. Per-wave structure identical to the proven round-8 kernel.
__global__ __launch_bounds__(1024) void mmd_main(const short* __restrict__ xf,
                                                 const float* __restrict__ sq2,
                                                 float* __restrict__ p1) {
    const int wid  = threadIdx.x >> 6;          // 0..15
    const int lane = threadIdx.x & 63;
    const int k = blockIdx.x * 4 + (wid >> 2);  // this wave's tile
    const int quad = wid & 3;
    const int wr = quad >> 1, wc = quad & 1;    // 64x64 quadrant within 128x128

    // linear upper-tri index -> (tr, tc), tr <= tc
    int tr = (int)((129.0f - sqrtf(16641.0f - 8.0f * (float)k)) * 0.5f);
    while (tr * NTILE - tr * (tr - 1) / 2 > k) --tr;
    while ((tr + 1) * NTILE - (tr + 1) * tr / 2 <= k) ++tr;
    const int tc = tr + (k - (tr * NTILE - tr * (tr - 1) / 2));
    const float w = (tc == tr) ? 1.0f : 2.0f;

    const int crow0 = (lane >> 4) * 4;          // C/D: row=(lane>>4)*4+reg, col=lane&15
    const int ccol  = lane & 15;

    const short* baseA = xf + (size_t)(tr * 16 + wr * 8) * 512 + lane * 8;
    const short* baseB = xf + (size_t)(tc * 16 + wc * 8) * 512 + lane * 8;

    // all 16 fragment loads issued back-to-back (proven best structure)
    short8 a[2][4], b[2][4];
    #pragma unroll
    for (int ks = 0; ks < 2; ks++)
        #pragma unroll
        for (int m = 0; m < 4; m++)
            a[ks][m] = *(const short8*)(baseA + (m * 2 + ks) * 512);
    #pragma unroll
    for (int ks = 0; ks < 2; ks++)
        #pragma unroll
        for (int n = 0; n < 4; n++)
            b[ks][n] = *(const short8*)(baseB + (n * 2 + ks) * 512);

    const int brow = tr * 128 + wr * 64;
    const int bcol = tc * 128 + wc * 64;
    float sqrl[16];
    #pragma unroll
    for (int m = 0; m < 4; m++) {
        const float4 f = *(const float4*)(sq2 + brow + m * 16 + crow0);
        sqrl[4*m+0] = f.x; sqrl[4*m+1] = f.y; sqrl[4*m+2] = f.z; sqrl[4*m+3] = f.w;
    }
    float sqcl[4];
    #pragma unroll
    for (int n = 0; n < 4; n++)
        sqcl[n] = sq2[bcol + n * 16 + ccol];

    f32x4 c[4][4];
    #pragma unroll
    for (int m = 0; m < 4; m++)
        #pragma unroll
        for (int n = 0; n < 4; n++)
            c[m][n] = (f32x4){0.f, 0.f, 0.f, 0.f};

    #pragma unroll
    for (int ks = 0; ks < 2; ks++)
        #pragma unroll
        for (int m = 0; m < 4; m++)
            #pragma unroll
            for (int n = 0; n < 4; n++)
                c[m][n] = __builtin_amdgcn_mfma_f32_16x16x32_bf16(a[ks][m], b[ks][n], c[m][n], 0, 0, 0);

    // epilogue: sum exp2(L2E*sq_r + L2E*sq_c - 2*L2E*g)
    float acc4[4] = {0.f, 0.f, 0.f, 0.f};
    #pragma unroll
    for (int n = 0; n < 4; n++)
        #pragma unroll
        for (int m = 0; m < 4; m++)
            #pragma unroll
            for (int r = 0; r < 4; r++)
                acc4[r] += fast_exp2(fmaf(-2.0f * L2E, c[m][n][r], sqrl[m * 4 + r] + sqcl[n]));

    float local = ((acc4[0] + acc4[1]) + (acc4[2] + acc4[3])) * w;
    #pragma unroll
    for (int off = 32; off; off >>= 1) local += __shfl_down(local, off, 64);
    __shared__ float red[16];
    if (lane == 0) red[wid] = local;
    __syncthreads();
    if (threadIdx.x == 0) {
        float t = 0.f;
        #pragma unroll
        for (int i = 0; i < 16; i++) t += red[i];
        p1[blockIdx.x] = t;
    }
}

__global__ void finalize_kernel(const float* __restrict__ p1, const float* __restrict__ p3,
                                float* __restrict__ out) {
    const int lane = threadIdx.x & 63;
    const int wid  = threadIdx.x >> 6;
    float s1 = 0.f, s3 = 0.f;
    for (int i = threadIdx.x; i < NQUAD; i += 256) s1 += p1[i];
    for (int i = threadIdx.x; i < NPREP; i += 256) s3 += p3[i];
    #pragma unroll
    for (int off = 32; off; off >>= 1) {
        s1 += __shfl_down(s1, off, 64);
        s3 += __shfl_down(s3, off, 64);
    }
    __shared__ float r1[4], r3[4];
    if (lane == 0) { r1[wid] = s1; r3[wid] = s3; }
    __syncthreads();
    if (threadIdx.x == 0) {
        const float t1 = (r1[0] + r1[1] + r1[2] + r1[3]) / ((float)TT * (float)TT);
        const float t3 = (r3[0] + r3[1] + r3[2] + r3[3]) / (float)TT;
        out[0] = t1 + 1.0f + t3;
    }
}

extern "C" void kernel_launch(void* const* d_in, const int* in_sizes, int n_in,
                              void* d_out, int out_size, void* d_ws, size_t ws_size,
                              hipStream_t stream) {
    const float* x = (const float*)d_in[0];   // xs: [4, 8192, 64] f32; only batch 0 used
    float* out = (float*)d_out;
    char* ws = (char*)d_ws;

    float* sq2 = (float*)ws;
    short* xf = (short*)(ws + TT * sizeof(float));
    float* p1 = (float*)(ws + TT * sizeof(float) + (size_t)TT * DD * sizeof(short));
    float* p3 = p1 + NQUAD;

    prep_kernel<<<NPREP, 256, 0, stream>>>(x, sq2, xf, p3);
    mmd_main<<<NQUAD, 1024, 0, stream>>>(xf, sq2, p1);
    finalize_kernel<<<1, 256, 0, stream>>>(p1, p3, out);
}

// Round 12
// 24.751 us; speedup vs baseline: 1.1001x; 1.1001x over previous
//
#include <hip/hip_runtime.h>
#include <hip/hip_bf16.h>

#define TT 8192
#define DD 64
#define NTILE 64                        // 8192 / 128
#define NBLK (NTILE * (NTILE + 1) / 2)  // 2080 upper-tri 128x128 tiles
#define NPAIR (NBLK / 2)                // 1040 blocks, 2 tiles each
#define NXCD 8
#define NPREP 256                       // prep blocks (32 rows each)
#define L2E 1.4426950408889634f

typedef __attribute__((ext_vector_type(8))) short short8;
typedef __attribute__((ext_vector_type(4))) float f32x4;

static __device__ __forceinline__ float fast_exp2(float x) {
#if __has_builtin(__builtin_amdgcn_exp2f)
    return __builtin_amdgcn_exp2f(x);
#else
    float r; asm volatile("v_exp_f32 %0, %1" : "=v"(r) : "v"(x)); return r;
#endif
}

// Fragment-ready layout: for rowgroup rg = row/16, ks = k/32:
//   flat elem index = (rg*2 + ks)*512 + ((k%32)/8)*128 + (row%16)*8 + (k%8)
// A wave's MFMA fragment load for (rg, ks) is xf_base + lane*8 elems --
// one contiguous 1 KB burst per instruction.
//
// ws layout:
//   [0]        float sq2[8192]     (L2E * ||x_i||^2)
//   [+32KB]    short xf[8192*64]   (1 MB, fragment-tiled bf16)
//   [+32KB+1MB]float p1[1040]; float p3[256]

__global__ __launch_bounds__(256) void prep_kernel(const float* __restrict__ x,
                                                   float* __restrict__ sq2,
                                                   short* __restrict__ xf,
                                                   float* __restrict__ p3) {
    const int tid = threadIdx.x;
    const int r   = tid >> 3;           // 0..31 row within block
    const int ch  = tid & 7;            // 0..7, 8-element k-chunk
    const int row = blockIdx.x * 32 + r;

    const float4 u = *(const float4*)(x + (size_t)row * DD + ch * 8);
    const float4 v = *(const float4*)(x + (size_t)row * DD + ch * 8 + 4);
    short8 s8;
    s8[0] = __builtin_bit_cast(short, __float2bfloat16(u.x));
    s8[1] = __builtin_bit_cast(short, __float2bfloat16(u.y));
    s8[2] = __builtin_bit_cast(short, __float2bfloat16(u.z));
    s8[3] = __builtin_bit_cast(short, __float2bfloat16(u.w));
    s8[4] = __builtin_bit_cast(short, __float2bfloat16(v.x));
    s8[5] = __builtin_bit_cast(short, __float2bfloat16(v.y));
    s8[6] = __builtin_bit_cast(short, __float2bfloat16(v.z));
    s8[7] = __builtin_bit_cast(short, __float2bfloat16(v.w));

    const size_t F = (size_t)(row >> 4) * 1024 + (size_t)(ch >> 2) * 512
                   + (size_t)(ch & 3) * 128 + (size_t)(row & 15) * 8;
    *(short8*)(xf + F) = s8;

    float s = u.x*u.x + u.y*u.y + u.z*u.z + u.w*u.w
            + v.x*v.x + v.y*v.y + v.z*v.z + v.w*v.w;
    s += __shfl_xor(s, 1, 64);
    s += __shfl_xor(s, 2, 64);
    s += __shfl_xor(s, 4, 64);

    __shared__ float e3[32];
    if (ch == 0) {
        sq2[row] = L2E * s;
        e3[r] = __expf(s);
    }
    __syncthreads();
    if (tid == 0) {
        float t = 0.f;
        #pragma unroll
        for (int i = 0; i < 32; i++) t += e3[i];
        p3[blockIdx.x] = t;
    }
}

// 512 threads = 8 waves; waves 0-3 own tile 2k, waves 4-7 own tile 2k+1.
// XCD-aware swizzle: 1040 % 8 == 0, each XCD gets a contiguous band of
// 130 pair-blocks (adjacent tiles sharing A-row panels -> local-L2 reuse).
__global__ __launch_bounds__(512, 4) void mmd_main(const short* __restrict__ xf,
                                                   const float* __restrict__ sq2,
                                                   float* __restrict__ p1) {
    const int swz = (blockIdx.x % NXCD) * (NPAIR / NXCD) + blockIdx.x / NXCD;

    const int wid  = threadIdx.x >> 6;          // 0..7
    const int lane = threadIdx.x & 63;
    const int k = swz * 2 + (wid >> 2);         // this wave's tile
    const int quad = wid & 3;
    const int wr = quad >> 1, wc = quad & 1;    // 64x64 quadrant within 128x128

    // linear upper-tri index -> (tr, tc), tr <= tc
    int tr = (int)((129.0f - sqrtf(16641.0f - 8.0f * (float)k)) * 0.5f);
    while (tr * NTILE - tr * (tr - 1) / 2 > k) --tr;
    while ((tr + 1) * NTILE - (tr + 1) * tr / 2 <= k) ++tr;
    const int tc = tr + (k - (tr * NTILE - tr * (tr - 1) / 2));
    const float w = (tc == tr) ? 1.0f : 2.0f;

    const int crow0 = (lane >> 4) * 4;          // C/D: row=(lane>>4)*4+reg, col=lane&15
    const int ccol  = lane & 15;

    const short* baseA = xf + (size_t)(tr * 16 + wr * 8) * 512 + lane * 8;
    const short* baseB = xf + (size_t)(tc * 16 + wc * 8) * 512 + lane * 8;

    // all 16 fragment loads issued back-to-back (proven best structure)
    short8 a[2][4], b[2][4];
    #pragma unroll
    for (int ks = 0; ks < 2; ks++)
        #pragma unroll
        for (int m = 0; m < 4; m++)
            a[ks][m] = *(const short8*)(baseA + (m * 2 + ks) * 512);
    #pragma unroll
    for (int ks = 0; ks < 2; ks++)
        #pragma unroll
        for (int n = 0; n < 4; n++)
            b[ks][n] = *(const short8*)(baseB + (n * 2 + ks) * 512);

    const int brow = tr * 128 + wr * 64;
    const int bcol = tc * 128 + wc * 64;
    float sqrl[16];
    #pragma unroll
    for (int m = 0; m < 4; m++) {
        const float4 f = *(const float4*)(sq2 + brow + m * 16 + crow0);
        sqrl[4*m+0] = f.x; sqrl[4*m+1] = f.y; sqrl[4*m+2] = f.z; sqrl[4*m+3] = f.w;
    }
    float sqcl[4];
    #pragma unroll
    for (int n = 0; n < 4; n++)
        sqcl[n] = sq2[bcol + n * 16 + ccol];

    f32x4 c[4][4];
    #pragma unroll
    for (int m = 0; m < 4; m++)
        #pragma unroll
        for (int n = 0; n < 4; n++)
            c[m][n] = (f32x4){0.f, 0.f, 0.f, 0.f};

    #pragma unroll
    for (int ks = 0; ks < 2; ks++)
        #pragma unroll
        for (int m = 0; m < 4; m++)
            #pragma unroll
            for (int n = 0; n < 4; n++)
                c[m][n] = __builtin_amdgcn_mfma_f32_16x16x32_bf16(a[ks][m], b[ks][n], c[m][n], 0, 0, 0);

    // epilogue: sum exp2(L2E*sq_r + L2E*sq_c - 2*L2E*g)
    float acc4[4] = {0.f, 0.f, 0.f, 0.f};
    #pragma unroll
    for (int n = 0; n < 4; n++)
        #pragma unroll
        for (int m = 0; m < 4; m++)
            #pragma unroll
            for (int r = 0; r < 4; r++)
                acc4[r] += fast_exp2(fmaf(-2.0f * L2E, c[m][n][r], sqrl[m * 4 + r] + sqcl[n]));

    float local = ((acc4[0] + acc4[1]) + (acc4[2] + acc4[3])) * w;
    #pragma unroll
    for (int off = 32; off; off >>= 1) local += __shfl_down(local, off, 64);
    __shared__ float red[8];
    if (lane == 0) red[wid] = local;
    __syncthreads();
    if (threadIdx.x == 0) {
        float t = 0.f;
        #pragma unroll
        for (int i = 0; i < 8; i++) t += red[i];
        p1[swz] = t;
    }
}

__global__ void finalize_kernel(const float* __restrict__ p1, const float* __restrict__ p3,
                                float* __restrict__ out) {
    const int lane = threadIdx.x & 63;
    const int wid  = threadIdx.x >> 6;
    float s1 = 0.f, s3 = 0.f;
    for (int i = threadIdx.x; i < NPAIR; i += 256) s1 += p1[i];
    for (int i = threadIdx.x; i < NPREP; i += 256) s3 += p3[i];
    #pragma unroll
    for (int off = 32; off; off >>= 1) {
        s1 += __shfl_down(s1, off, 64);
        s3 += __shfl_down(s3, off, 64);
    }
    __shared__ float r1[4], r3[4];
    if (lane == 0) { r1[wid] = s1; r3[wid] = s3; }
    __syncthreads();
    if (threadIdx.x == 0) {
        const float t1 = (r1[0] + r1[1] + r1[2] + r1[3]) / ((float)TT * (float)TT);
        const float t3 = (r3[0] + r3[1] + r3[2] + r3[3]) / (float)TT;
        out[0] = t1 + 1.0f + t3;
    }
}

extern "C" void kernel_launch(void* const* d_in, const int* in_sizes, int n_in,
                              void* d_out, int out_size, void* d_ws, size_t ws_size,
                              hipStream_t stream) {
    const float* x = (const float*)d_in[0];   // xs: [4, 8192, 64] f32; only batch 0 used
    float* out = (float*)d_out;
    char* ws = (char*)d_ws;

    float* sq2 = (float*)ws;
    short* xf = (short*)(ws + TT * sizeof(float));
    float* p1 = (float*)(ws + TT * sizeof(float) + (size_t)TT * DD * sizeof(short));
    float* p3 = p1 + NPAIR;

    prep_kernel<<<NPREP, 256, 0, stream>>>(x, sq2, xf, p3);
    mmd_main<<<NPAIR, 512, 0, stream>>>(xf, sq2, p1);
    finalize_kernel<<<1, 256, 0, stream>>>(p1, p3, out);
}